// Round 16
// baseline (354.347 us; speedup 1.0000x reference)
//
#include <hip/hip_runtime.h>
#include <hip/hip_bf16.h>

#define N_PTS 2048
#define BATCH 2
#define KNN 40

typedef __attribute__((ext_vector_type(8))) short bf16x8;
typedef __attribute__((ext_vector_type(16))) float f32x16;

__device__ __forceinline__ float lrelu(float v, float s) {
    return v >= 0.f ? v : s * v;
}

// ---------------- prefix body: conv (5,3)/(5,1) + lrelu(0.01) -> H (B,N,2) --------------
__device__ __forceinline__ void prefix_body(int fb, const float* __restrict__ x,
                                            const float* __restrict__ Wc,
                                            const float* __restrict__ bc,
                                            float* __restrict__ H) {
    int t = fb * 256 + threadIdx.x;
    if (t >= BATCH * N_PTS) return;
    int b = t >> 11, n = t & 2047;
    #pragma unroll
    for (int oh = 0; oh < 2; ++oh) {
        float acc = bc[0];
        #pragma unroll
        for (int kh = 0; kh < 5; ++kh) {
            const float* xr = x + ((size_t)b * 10 + oh * 5 + kh) * N_PTS;
            #pragma unroll
            for (int kw = 0; kw < 3; ++kw) {
                int nn = n + kw - 1;
                if (nn >= 0 && nn < N_PTS) acc += xr[nn] * Wc[kh * 3 + kw];
            }
        }
        H[(size_t)t * 2 + oh] = lrelu(acc, 0.01f);
    }
}

// ---------------- cvt body: fp32 -> bf16 hi/lo split (contiguous) ----------------
__device__ __forceinline__ void cvt_body(int t, const float* __restrict__ src,
                                         short* __restrict__ hi, short* __restrict__ lo,
                                         int total4) {
    if (t >= total4) return;
    float4 v = ((const float4*)src)[t];
    short4 h, l;
    #pragma unroll
    for (int j = 0; j < 4; ++j) {
        float xv = (&v.x)[j];
        __hip_bfloat16 hb = __float2bfloat16(xv);
        float hf = __bfloat162float(hb);
        __hip_bfloat16 lb = __float2bfloat16(xv - hf);
        (&h.x)[j] = *reinterpret_cast<short*>(&hb);
        (&l.x)[j] = *reinterpret_cast<short*>(&lb);
    }
    ((short4*)hi)[t] = h;
    ((short4*)lo)[t] = l;
}

// ---------------- prefix + W5 split co-launch (both depend only on inputs) --------------
__global__ __launch_bounds__(256) void prefix_cvt_kernel(const float* __restrict__ x,
                                                         const float* __restrict__ Wc,
                                                         const float* __restrict__ bc,
                                                         float* __restrict__ H,
                                                         const float* __restrict__ W5,
                                                         short* __restrict__ W5h,
                                                         short* __restrict__ W5l) {
    int fb = blockIdx.x;
    if (fb < 16) prefix_body(fb, x, Wc, bc, H);
    else cvt_body((fb - 16) * 256 + threadIdx.x, W5, W5h, W5l, 1024 * 512 / 4);
}

// ---------------- gram small (C=2, stage 1): 64x64 tile, fused xx, fp32 ----------------
__global__ __launch_bounds__(256) void gram_small_kernel(const float* __restrict__ X, long bsX,
                                                         long nstride,
                                                         float* __restrict__ negd) {
    __shared__ float AsT[2][68];
    __shared__ float BsT[2][68];
    __shared__ float xxr[64];
    __shared__ float xxc[64];
    int bz = blockIdx.z;
    const float* Xb = X + (size_t)bz * bsX;
    float* nd = negd + (size_t)bz * nstride;
    int tid = threadIdx.x;
    int r0 = blockIdx.y * 64, c0 = blockIdx.x * 64;
    int ty = tid >> 4, tx = tid & 15;
    if (tid < 128) {
        int r = tid >> 1, c = tid & 1;
        AsT[c][r] = Xb[(size_t)(r0 + r) * 2 + c];
        BsT[c][r] = Xb[(size_t)(c0 + r) * 2 + c];
        int v = (tid < 64) ? (r0 + tid) : (c0 + tid - 64);
        float x0 = Xb[(size_t)v * 2], x1 = Xb[(size_t)v * 2 + 1];
        float s = 0.f;
        s += x0 * x0;
        s += x1 * x1;
        if (tid < 64) xxr[tid] = s; else xxc[tid - 64] = s;
    }
    __syncthreads();
    float acc[4][4] = {};
    #pragma unroll
    for (int k = 0; k < 2; ++k) {
        float4 a = *(const float4*)&AsT[k][ty * 4];
        float4 b = *(const float4*)&BsT[k][tx * 4];
        #pragma unroll
        for (int i = 0; i < 4; ++i)
            #pragma unroll
            for (int j = 0; j < 4; ++j)
                acc[i][j] += (&a.x)[i] * (&b.x)[j];
    }
    #pragma unroll
    for (int i = 0; i < 4; ++i) {
        int r = r0 + ty * 4 + i;
        float xr = xxr[ty * 4 + i];
        #pragma unroll
        for (int j = 0; j < 4; ++j) {
            int c = c0 + tx * 4 + j;
            nd[(size_t)r * N_PTS + c] = 2.0f * acc[i][j] - xr - xxc[tx * 4 + j];
        }
    }
}

// ---------------- gram MFMA (C=64/128): 64x32 per wave, 64x128 per block ----------------
// split-bf16 3-pass, L2-direct, low-VGPR (2 f32x16 acc, no manual double-buffer).
// grid (16, 32, B) = 1024 blocks -> 4 blocks/CU. Per-acc MFMA order identical to the
// previous 128x128 kernel -> NEGD bit-identical.
template<int C, int STAGE>
__global__ __launch_bounds__(256) void gram_mfma_kernel(
        const short* __restrict__ Xh, const short* __restrict__ Xl, long bsX, int S,
        const float* __restrict__ xx, long xxstride,
        float* __restrict__ negd, long nstride) {
    constexpr int NCH = C / 16;
    __shared__ float xr_s[64];
    __shared__ float xc_s[128];
    int bz = blockIdx.z;
    const short* Ah = Xh + (size_t)bz * bsX;
    const short* Al = Xl + (size_t)bz * bsX;
    const float* xxb = xx + (size_t)bz * xxstride;
    float* nd = negd + (size_t)bz * nstride;
    int tid = threadIdx.x;
    int wave = tid >> 6, lane = tid & 63;
    int r0 = blockIdx.y * 64;            // 64 rows per block
    int c0 = blockIdx.x * 128;           // 128 cols per block (32 per wave)
    int cw = c0 + wave * 32;
    int rr = lane & 31, kg = lane >> 5;
    if (tid < 64) xr_s[tid] = xxb[r0 + tid];
    else if (tid < 192) xc_s[tid - 64] = xxb[c0 + (tid - 64)];
    const int FS = 32 * S;
    const short* pAh = Ah + (size_t)(r0 + rr) * S + kg * 8;
    const short* pAl = Al + (size_t)(r0 + rr) * S + kg * 8;
    const short* pBh = Ah + (size_t)(cw + rr) * S + kg * 8;
    const short* pBl = Al + (size_t)(cw + rr) * S + kg * 8;
    f32x16 a0 = {}, a1 = {};
    #pragma unroll 2
    for (int kc = 0; kc < NCH; ++kc) {
        int kn = kc * 16;
        bf16x8 ah0 = *(const bf16x8*)(pAh + kn);
        bf16x8 ah1 = *(const bf16x8*)(pAh + kn + FS);
        bf16x8 al0 = *(const bf16x8*)(pAl + kn);
        bf16x8 al1 = *(const bf16x8*)(pAl + kn + FS);
        bf16x8 bh = *(const bf16x8*)(pBh + kn);
        bf16x8 bl = *(const bf16x8*)(pBl + kn);
        a0 = __builtin_amdgcn_mfma_f32_32x32x16_bf16(ah0, bh, a0, 0, 0, 0);
        a0 = __builtin_amdgcn_mfma_f32_32x32x16_bf16(ah0, bl, a0, 0, 0, 0);
        a0 = __builtin_amdgcn_mfma_f32_32x32x16_bf16(al0, bh, a0, 0, 0, 0);
        a1 = __builtin_amdgcn_mfma_f32_32x32x16_bf16(ah1, bh, a1, 0, 0, 0);
        a1 = __builtin_amdgcn_mfma_f32_32x32x16_bf16(ah1, bl, a1, 0, 0, 0);
        a1 = __builtin_amdgcn_mfma_f32_32x32x16_bf16(al1, bh, a1, 0, 0, 0);
    }
    __syncthreads();
    // C/D layout: col = lane&31, row = (reg&3) + 8*(reg>>2) + 4*(lane>>5)
    int colF = lane & 31;
    int hi4 = (lane >> 5) * 4;
    int cIn = wave * 32 + colF;
    float xc = xc_s[cIn];
    float* ndr = nd + (size_t)r0 * N_PTS + c0 + cIn;
    #pragma unroll
    for (int reg = 0; reg < 16; ++reg) {
        int rIn0 = (reg & 3) + 8 * (reg >> 2) + hi4;
        ndr[(size_t)rIn0 * N_PTS] = 2.0f * a0[reg] - xr_s[rIn0] - xc;
        int rIn1 = 32 + rIn0;
        ndr[(size_t)rIn1 * N_PTS] = 2.0f * a1[reg] - xr_s[rIn1] - xc;
    }
}

// ---------------- top-40 per row: single-pass radix select (11/11/10 bits) ---------------
template<int STAGE>
__global__ __launch_bounds__(256) void topk_kernel(const float* __restrict__ negd, long nstride,
                                                   int* __restrict__ idx_out) {
    __shared__ unsigned hist[2048];
    __shared__ unsigned cand[2048];
    __shared__ unsigned wsum[4];
    __shared__ unsigned sc[4];
    __shared__ unsigned tieb;
    int bz = blockIdx.y;
    int n = blockIdx.x;
    int tid = threadIdx.x;
    int wave = tid >> 6, lane = tid & 63;
    const float* row = negd + (size_t)bz * nstride + (size_t)n * N_PTS;
    float4 v0 = ((const float4*)row)[tid];
    float4 v1 = ((const float4*)row)[tid + 256];
    unsigned k0[4], k1[4];
    #pragma unroll
    for (int e = 0; e < 4; ++e) {
        unsigned u = __float_as_uint((&v0.x)[e]);
        k0[e] = (u & 0x80000000u) ? ~u : (u | 0x80000000u);
        u = __float_as_uint((&v1.x)[e]);
        k1[e] = (u & 0x80000000u) ? ~u : (u | 0x80000000u);
    }
    for (int i = tid; i < 2048; i += 256) hist[i] = 0u;
    if (tid == 0) { sc[2] = 0u; sc[3] = 0u; }
    __syncthreads();
    #pragma unroll
    for (int e = 0; e < 4; ++e) {
        atomicAdd(&hist[k0[e] >> 21], 1u);
        atomicAdd(&hist[k1[e] >> 21], 1u);
    }
    __syncthreads();
    unsigned r = KNN;
    {
        unsigned chunk = 0;
        #pragma unroll
        for (int q = 0; q < 8; ++q) chunk += hist[tid * 8 + q];
        unsigned s = chunk;
        #pragma unroll
        for (int off = 1; off < 64; off <<= 1) {
            unsigned v = __shfl_down(s, off);
            if (lane + off < 64) s += v;
        }
        if (lane == 0) wsum[wave] = s;
        __syncthreads();
        unsigned add = 0;
        for (int w = wave + 1; w < 4; ++w) add += wsum[w];
        unsigned St = s + add, Sn = St - chunk;
        if (St >= r && Sn < r) { sc[0] = (unsigned)tid; sc[1] = r - Sn; }
        __syncthreads();
        if (tid == 0) {
            int c = (int)sc[0]; unsigned rc = sc[1];
            unsigned cum = 0; int b = c * 8 + 7;
            for (;; --b) { cum += hist[b]; if (cum >= rc) break; }
            sc[0] = (unsigned)b; sc[1] = rc - (cum - hist[b]);
        }
        __syncthreads();
    }
    unsigned p1 = sc[0]; r = sc[1];
    __syncthreads();
    for (int i = tid; i < 2048; i += 256) hist[i] = 0u;
    __syncthreads();
    int* out = idx_out + ((size_t)bz * N_PTS + n) * KNN;
    #pragma unroll
    for (int h = 0; h < 2; ++h) {
        #pragma unroll
        for (int e = 0; e < 4; ++e) {
            unsigned u = (h == 0) ? k0[e] : k1[e];
            int j = (tid + h * 256) * 4 + e;
            unsigned b = u >> 21;
            if (b > p1) {
                out[atomicAdd(&sc[2], 1u)] = j;
            } else if (b == p1) {
                unsigned low = u & 0x1FFFFFu;
                cand[atomicAdd(&sc[3], 1u)] = (low << 11) | (unsigned)j;
                atomicAdd(&hist[low >> 10], 1u);
            }
        }
    }
    __syncthreads();
    int cnt = (int)sc[3];
    {
        unsigned chunk = 0;
        #pragma unroll
        for (int q = 0; q < 8; ++q) chunk += hist[tid * 8 + q];
        unsigned s = chunk;
        #pragma unroll
        for (int off = 1; off < 64; off <<= 1) {
            unsigned v = __shfl_down(s, off);
            if (lane + off < 64) s += v;
        }
        if (lane == 0) wsum[wave] = s;
        __syncthreads();
        unsigned add = 0;
        for (int w = wave + 1; w < 4; ++w) add += wsum[w];
        unsigned St = s + add, Sn = St - chunk;
        if (St >= r && Sn < r) { sc[0] = (unsigned)tid; sc[1] = r - Sn; }
        __syncthreads();
        if (tid == 0) {
            int c = (int)sc[0]; unsigned rc = sc[1];
            unsigned cum = 0; int b = c * 8 + 7;
            for (;; --b) { cum += hist[b]; if (cum >= rc) break; }
            sc[0] = (unsigned)b; sc[1] = rc - (cum - hist[b]);
        }
        __syncthreads();
    }
    unsigned b2 = sc[0]; r = sc[1];
    __syncthreads();
    for (int i = tid; i < 1024; i += 256) hist[i] = 0u;
    __syncthreads();
    for (int i = tid; i < cnt; i += 256) {
        unsigned p = cand[i];
        if ((p >> 21) == b2) atomicAdd(&hist[(p >> 11) & 0x3FFu], 1u);
    }
    __syncthreads();
    {
        unsigned chunk = 0;
        #pragma unroll
        for (int q = 0; q < 4; ++q) chunk += hist[tid * 4 + q];
        unsigned s = chunk;
        #pragma unroll
        for (int off = 1; off < 64; off <<= 1) {
            unsigned v = __shfl_down(s, off);
            if (lane + off < 64) s += v;
        }
        if (lane == 0) wsum[wave] = s;
        __syncthreads();
        unsigned add = 0;
        for (int w = wave + 1; w < 4; ++w) add += wsum[w];
        unsigned St = s + add, Sn = St - chunk;
        if (St >= r && Sn < r) { sc[0] = (unsigned)tid; sc[1] = r - Sn; }
        __syncthreads();
        if (tid == 0) {
            int c = (int)sc[0]; unsigned rc = sc[1];
            unsigned cum = 0; int b = c * 4 + 3;
            for (;; --b) { cum += hist[b]; if (cum >= rc) break; }
            sc[0] = (unsigned)b; sc[1] = rc - (cum - hist[b]);
        }
        __syncthreads();
    }
    unsigned Tlow = (b2 << 10) | sc[0];
    unsigned r3 = sc[1];
    __syncthreads();
    for (int i = tid; i < cnt; i += 256) {
        unsigned p = cand[i];
        if ((p >> 11) > Tlow) out[atomicAdd(&sc[2], 1u)] = (int)(p & 0x7FFu);
    }
    __syncthreads();
    int last = -1;
    for (unsigned t = 0; t < r3; ++t) {
        unsigned m = 0xFFFFFFFFu;
        for (int i = tid; i < cnt; i += 256) {
            unsigned p = cand[i];
            if ((p >> 11) == Tlow) {
                int j = (int)(p & 0x7FFu);
                if (j > last && (unsigned)j < m) m = (unsigned)j;
            }
        }
        hist[tid] = m;
        __syncthreads();
        for (int st = 128; st >= 1; st >>= 1) {
            if (tid < st) hist[tid] = min(hist[tid], hist[tid + st]);
            __syncthreads();
        }
        if (tid == 0) { out[KNN - (int)r3 + (int)t] = (int)hist[0]; tieb = hist[0]; }
        __syncthreads();
        last = (int)tieb;
    }
}

// ---------------- YaT = X @ Wa^T ; ZT = X @ Wb^T - YaT + bias  (layout (B,N,O)) ---------
template<int C, int O, int STAGE>
__global__ __launch_bounds__(256) void ya_z_kernel(const float* __restrict__ X, int S, long bsX,
                                                   const float* __restrict__ W,
                                                   const float* __restrict__ bias,
                                                   float* __restrict__ YaT, float* __restrict__ ZT) {
    constexpr int KC = (C < 32) ? C : 32;
    __shared__ float Xs[16][KC + 1];
    __shared__ float WaS[KC][64];
    __shared__ float WbS[KC][64];
    int b = blockIdx.z;
    const float* Xb = X + (size_t)b * bsX;
    int n0 = blockIdx.x * 16, o0 = blockIdx.y * 64;
    int tid = threadIdx.x, ty = tid >> 4, tx = tid & 15;
    float aa[4] = {}, ab[4] = {};
    for (int k0 = 0; k0 < C; k0 += KC) {
        __syncthreads();
        for (int i = tid; i < 16 * KC; i += 256) {
            int rw = i / KC, c = i % KC;
            Xs[rw][c] = Xb[(size_t)(n0 + rw) * S + k0 + c];
        }
        for (int i = tid; i < 64 * KC; i += 256) {
            int rw = i / KC, c = i % KC;
            int scol = rw ^ ((c & 15) << 2);
            WaS[c][scol] = W[(size_t)(o0 + rw) * 2 * C + k0 + c];
            WbS[c][scol] = W[(size_t)(o0 + rw) * 2 * C + C + k0 + c];
        }
        __syncthreads();
        #pragma unroll
        for (int k = 0; k < KC; ++k) {
            float xv = Xs[ty][k];
            int m = (k & 15) << 2;
            float4 wa = *(const float4*)&WaS[k][(tx * 4) ^ m];
            float4 wb = *(const float4*)&WbS[k][(tx * 4) ^ m];
            #pragma unroll
            for (int j = 0; j < 4; ++j) {
                aa[j] += xv * (&wa.x)[j];
                ab[j] += xv * (&wb.x)[j];
            }
        }
    }
    int n = n0 + ty;
    float4 ya, zt;
    #pragma unroll
    for (int j = 0; j < 4; ++j) {
        int o = o0 + tx * 4 + j;
        (&ya.x)[j] = aa[j];
        (&zt.x)[j] = ab[j] - aa[j] + bias[o];
    }
    size_t off = ((size_t)b * N_PTS + n) * O + o0 + tx * 4;
    *(float4*)&YaT[off] = ya;
    *(float4*)&ZT[off] = zt;
}

// ---------------- edge reduce (vectorized x4) + fused bf16-split + xx for next stage ----
template<int O, int STAGE, int AUX>
__global__ __launch_bounds__(256) void edge_reduce_kernel(const float* __restrict__ YaT,
                                                          const float* __restrict__ ZT,
                                                          const int* __restrict__ IDX,
                                                          float* __restrict__ CATp,
                                                          short* __restrict__ CATh,
                                                          short* __restrict__ CATl,
                                                          float* __restrict__ XX, int coloff) {
    constexpr int TPR = O / 4;           // threads per row
    int b = blockIdx.y;
    int tid = threadIdx.x;
    int n = blockIdx.x * (256 / TPR) + tid / TPR;
    int o = (tid % TPR) * 4;
    const float* Ya_b = YaT + (size_t)b * N_PTS * O;
    size_t rowoff = (size_t)b * N_PTS + n;
    float4 z = *(const float4*)&ZT[rowoff * O + o];
    const int* ir = IDX + rowoff * KNN;
    float4 acc = {-3.4e38f, -3.4e38f, -3.4e38f, -3.4e38f};
    #pragma unroll 8
    for (int k = 0; k < KNN; ++k) {
        int m = ir[k];
        float4 v = *(const float4*)&Ya_b[(size_t)m * O + o];
        acc.x = fmaxf(acc.x, lrelu(v.x + z.x, 0.2f));
        acc.y = fmaxf(acc.y, lrelu(v.y + z.y, 0.2f));
        acc.z = fmaxf(acc.z, lrelu(v.z + z.z, 0.2f));
        acc.w = fmaxf(acc.w, lrelu(v.w + z.w, 0.2f));
    }
    size_t coff = rowoff * 512 + coloff + o;
    *(float4*)&CATp[coff] = acc;
    short4 h, l;
    #pragma unroll
    for (int j = 0; j < 4; ++j) {
        float xv = (&acc.x)[j];
        __hip_bfloat16 hb = __float2bfloat16(xv);
        float hf = __bfloat162float(hb);
        __hip_bfloat16 lb = __float2bfloat16(xv - hf);
        (&h.x)[j] = *reinterpret_cast<short*>(&hb);
        (&l.x)[j] = *reinterpret_cast<short*>(&lb);
    }
    *(short4*)&CATh[coff] = h;
    *(short4*)&CATl[coff] = l;
    if (AUX) {
        float sq = acc.x * acc.x + acc.y * acc.y + acc.z * acc.z + acc.w * acc.w;
        #pragma unroll
        for (int off = 1; off < TPR; off <<= 1) sq += __shfl_xor(sq, off);
        if ((tid % TPR) == 0) XX[rowoff] = sq;
    }
}

// ---------------- w5max: split-bf16 3-pass MFMA, L2-direct ----------------
__global__ __launch_bounds__(256) void w5max_mfma_kernel(
        const short* __restrict__ Ah, const short* __restrict__ Al,
        const short* __restrict__ Bh, const short* __restrict__ Bl,
        const float* __restrict__ b5, float* __restrict__ PART) {
    __shared__ float red[2][128];
    int b = blockIdx.z;
    int tid = threadIdx.x;
    int wave = tid >> 6, lane = tid & 63;
    int wm = wave >> 1, wn = wave & 1;
    int m0 = blockIdx.x * 128 + wm * 64;
    int o0 = blockIdx.y * 128 + wn * 64;
    int rr = lane & 31;
    int kg = lane >> 5;
    const int FS = 32 * 512;
    const short* pAh = Ah + ((size_t)b * N_PTS + m0 + rr) * 512 + kg * 8;
    const short* pAl = Al + ((size_t)b * N_PTS + m0 + rr) * 512 + kg * 8;
    const short* pBh = Bh + (size_t)(o0 + rr) * 512 + kg * 8;
    const short* pBl = Bl + (size_t)(o0 + rr) * 512 + kg * 8;
    f32x16 a00 = {}, a01 = {}, a10 = {}, a11 = {};
    bf16x8 ah0 = *(const bf16x8*)(pAh);
    bf16x8 ah1 = *(const bf16x8*)(pAh + FS);
    bf16x8 al0 = *(const bf16x8*)(pAl);
    bf16x8 al1 = *(const bf16x8*)(pAl + FS);
    bf16x8 bh0 = *(const bf16x8*)(pBh);
    bf16x8 bh1 = *(const bf16x8*)(pBh + FS);
    bf16x8 bl0 = *(const bf16x8*)(pBl);
    bf16x8 bl1 = *(const bf16x8*)(pBl + FS);
    #pragma unroll 2
    for (int kc = 0; kc < 32; ++kc) {
        int kn = ((kc + 1) & 31) * 16;
        bf16x8 nah0 = *(const bf16x8*)(pAh + kn);
        bf16x8 nah1 = *(const bf16x8*)(pAh + kn + FS);
        bf16x8 nal0 = *(const bf16x8*)(pAl + kn);
        bf16x8 nal1 = *(const bf16x8*)(pAl + kn + FS);
        bf16x8 nbh0 = *(const bf16x8*)(pBh + kn);
        bf16x8 nbh1 = *(const bf16x8*)(pBh + kn + FS);
        bf16x8 nbl0 = *(const bf16x8*)(pBl + kn);
        bf16x8 nbl1 = *(const bf16x8*)(pBl + kn + FS);
        a00 = __builtin_amdgcn_mfma_f32_32x32x16_bf16(ah0, bh0, a00, 0, 0, 0);
        a00 = __builtin_amdgcn_mfma_f32_32x32x16_bf16(ah0, bl0, a00, 0, 0, 0);
        a00 = __builtin_amdgcn_mfma_f32_32x32x16_bf16(al0, bh0, a00, 0, 0, 0);
        a01 = __builtin_amdgcn_mfma_f32_32x32x16_bf16(ah0, bh1, a01, 0, 0, 0);
        a01 = __builtin_amdgcn_mfma_f32_32x32x16_bf16(ah0, bl1, a01, 0, 0, 0);
        a01 = __builtin_amdgcn_mfma_f32_32x32x16_bf16(al0, bh1, a01, 0, 0, 0);
        a10 = __builtin_amdgcn_mfma_f32_32x32x16_bf16(ah1, bh0, a10, 0, 0, 0);
        a10 = __builtin_amdgcn_mfma_f32_32x32x16_bf16(ah1, bl0, a10, 0, 0, 0);
        a10 = __builtin_amdgcn_mfma_f32_32x32x16_bf16(al1, bh0, a10, 0, 0, 0);
        a11 = __builtin_amdgcn_mfma_f32_32x32x16_bf16(ah1, bh1, a11, 0, 0, 0);
        a11 = __builtin_amdgcn_mfma_f32_32x32x16_bf16(ah1, bl1, a11, 0, 0, 0);
        a11 = __builtin_amdgcn_mfma_f32_32x32x16_bf16(al1, bh1, a11, 0, 0, 0);
        ah0 = nah0; ah1 = nah1; al0 = nal0; al1 = nal1;
        bh0 = nbh0; bh1 = nbh1; bl0 = nbl0; bl1 = nbl1;
    }
    #pragma unroll
    for (int fn = 0; fn < 2; ++fn) {
        float bo = b5[o0 + fn * 32 + rr];
        float m = -3.4e38f;
        #pragma unroll
        for (int r = 0; r < 16; ++r) {
            float v0 = (fn == 0) ? a00[r] : a01[r];
            float v1 = (fn == 0) ? a10[r] : a11[r];
            m = fmaxf(m, lrelu(v0 + bo, 0.2f));
            m = fmaxf(m, lrelu(v1 + bo, 0.2f));
        }
        m = fmaxf(m, __shfl_xor(m, 32));
        red[wm][wn * 64 + fn * 32 + rr] = m;
    }
    __syncthreads();
    if (tid < 128)
        PART[((size_t)b * 16 + blockIdx.x) * 1024 + blockIdx.y * 128 + tid] =
            fmaxf(red[0][tid], red[1][tid]);
}

__global__ void greduce_kernel(const float* __restrict__ PART, float* __restrict__ G) {
    int t = blockIdx.x * 256 + threadIdx.x;
    if (t >= BATCH * 1024) return;
    int b = t >> 10, o = t & 1023;
    const float* p = PART + (size_t)b * 16 * 1024 + o;
    float m = -3.4e38f;
    for (int nb = 0; nb < 16; ++nb) m = fmaxf(m, p[(size_t)nb * 1024]);
    G[t] = m;
}

// ---------------- FC: D0[b,j] = lrelu(g[b,:] . Wfc[j,:] + bfc[j]) ----------------
__global__ __launch_bounds__(256) void fc_kernel(const float* __restrict__ G,
                                                 const float* __restrict__ Wfc,
                                                 const float* __restrict__ bfc,
                                                 float* __restrict__ D0) {
    __shared__ float gl[2][1024];
    int tid = threadIdx.x;
    for (int i = tid; i < 2048; i += 256) gl[i >> 10][i & 1023] = G[i];
    __syncthreads();
    int wave = tid >> 6, lane = tid & 63;
    int j = blockIdx.x * 4 + wave;
    const float* wr = Wfc + (size_t)j * 1024;
    float a0 = 0.f, a1 = 0.f;
    for (int i = lane; i < 1024; i += 64) {
        float w = wr[i];
        a0 += w * gl[0][i];
        a1 += w * gl[1][i];
    }
    #pragma unroll
    for (int off = 32; off; off >>= 1) { a0 += __shfl_xor(a0, off); a1 += __shfl_xor(a1, off); }
    if (lane == 0) {
        float bb = bfc[j];
        D0[j] = lrelu(a0 + bb, 0.2f);
        D0[16384 + j] = lrelu(a1 + bb, 0.2f);
    }
}

// ---------------- fused up2 + conv3x3: quad kernel ----------------
template<int CI, int CO, int HI, int WI, int RELU>
__global__ __launch_bounds__(256) void upconv_quad_kernel(const float* __restrict__ in,
                                                          const float* __restrict__ W,
                                                          const float* __restrict__ bias,
                                                          float* __restrict__ out) {
    const int qid = blockIdx.x * 256 + threadIdx.x;
    const int p = qid / WI, q = qid % WI;
    const int co = blockIdx.y, b = blockIdx.z;
    const int HO = HI * 2, WO = WI * 2;
    int off[3][3];
    float msk[3][3];
    #pragma unroll
    for (int r = 0; r < 3; ++r) {
        int pr = p - 1 + r;
        float rm = (pr >= 0 && pr < HI) ? 1.f : 0.f;
        int prc = min(max(pr, 0), HI - 1);
        #pragma unroll
        for (int c = 0; c < 3; ++c) {
            int qc = q - 1 + c;
            float cm = (qc >= 0 && qc < WI) ? 1.f : 0.f;
            int qcc = min(max(qc, 0), WI - 1);
            off[r][c] = prc * WI + qcc;
            msk[r][c] = rm * cm;
        }
    }
    const float* inb = in + (size_t)(b * CI) * HI * WI;
    const float* wco = W + (size_t)co * CI * 9;
    float bb = bias[co];
    float a00 = bb, a01 = bb, a10 = bb, a11 = bb;
    const int me[3] = {0, 1, 1}, mo[3] = {1, 1, 2};
    #pragma unroll 4
    for (int ci = 0; ci < CI; ++ci) {
        const float* ip = inb + (size_t)ci * HI * WI;
        const float* wp = wco + ci * 9;
        float v[3][3];
        #pragma unroll
        for (int r = 0; r < 3; ++r)
            #pragma unroll
            for (int c = 0; c < 3; ++c)
                v[r][c] = msk[r][c] * ip[off[r][c]];
        #pragma unroll
        for (int dy = 0; dy < 3; ++dy) {
            #pragma unroll
            for (int dx = 0; dx < 3; ++dx) {
                float w = wp[dy * 3 + dx];
                a00 += w * v[me[dy]][me[dx]];
                a01 += w * v[me[dy]][mo[dx]];
                a10 += w * v[mo[dy]][me[dx]];
                a11 += w * v[mo[dy]][mo[dx]];
            }
        }
    }
    if (RELU) {
        a00 = lrelu(a00, 0.2f); a01 = lrelu(a01, 0.2f);
        a10 = lrelu(a10, 0.2f); a11 = lrelu(a11, 0.2f);
    }
    float* ob = out + ((size_t)(b * CO + co) * HO + 2 * p) * WO + 2 * q;
    float2 r0 = {a00, a01}, r1 = {a10, a11};
    *(float2*)ob = r0;
    *(float2*)(ob + WO) = r1;
}

extern "C" void kernel_launch(void* const* d_in, const int* in_sizes, int n_in,
                              void* d_out, int out_size, void* d_ws, size_t ws_size,
                              hipStream_t stream) {
    const float* x   = (const float*)d_in[0];
    const float* Wc  = (const float*)d_in[1];
    const float* bc  = (const float*)d_in[2];
    const float* W1  = (const float*)d_in[3];
    const float* b1  = (const float*)d_in[4];
    const float* W2  = (const float*)d_in[5];
    const float* b2  = (const float*)d_in[6];
    const float* W3  = (const float*)d_in[7];
    const float* b3  = (const float*)d_in[8];
    const float* W4  = (const float*)d_in[9];
    const float* b4  = (const float*)d_in[10];
    const float* W5  = (const float*)d_in[11];
    const float* b5  = (const float*)d_in[12];
    const float* Wfc = (const float*)d_in[13];
    const float* bfc = (const float*)d_in[14];
    const float* Wd1 = (const float*)d_in[15];
    const float* bd1 = (const float*)d_in[16];
    const float* Wd2 = (const float*)d_in[17];
    const float* bd2 = (const float*)d_in[18];
    const float* Wd3 = (const float*)d_in[19];
    const float* bd3 = (const float*)d_in[20];
    float* out = (float*)d_out;

    const long NST = (long)N_PTS * N_PTS;
    const size_t TAIL_SZ = 12214272ull;
    const size_t NEED_BATCHED = 16809984ull + 33554432ull + TAIL_SZ;  // 62,578,688
    const bool batched = ws_size >= NEED_BATCHED;
    const size_t negd_bytes = batched ? 33554432ull : 16777216ull;

    char* ws = (char*)d_ws;
    float* Hb   = (float*)(ws + 0);          // (B,N,2)
    float* CAT  = (float*)(ws + 32768);      // (B,N,512) fp32  8 MB
    float* YaT  = (float*)(ws + 8421376);    // (B,N,256)       4 MB
    float* ZT   = (float*)(ws + 12615680);   // (B,N,256)       4 MB
    float* NEGD = (float*)(ws + 16809984);   // (B?,N,N)     16/32 MB
    char* tail  = ws + 16809984 + negd_bytes;
    float* XX   = (float*)(tail);            // 16 KB
    int*   IDX  = (int*)  (tail + 16384);    // 640 KB
    float* PART = (float*)(tail + 671744);   // 128 KB
    float* G    = (float*)(tail + 802816);   // 8 KB
    float* D0   = (float*)(tail + 811008);   // 128 KB
    float* DEC1 = (float*)(tail + 942080);   // 256 KB
    float* DEC2 = (float*)(tail + 1204224);  // 512 KB
    short* W5h  = (short*)(tail + 1728512);  // 1 MB
    short* W5l  = (short*)(tail + 2777088);  // 1 MB
    short* CATh = (short*)(tail + 3825664);  // (B,N,512) bf16  4 MB
    short* CATl = (short*)(tail + 8019968);  // 4 MB

    // prefix + W5 split (both depend only on inputs)
    prefix_cvt_kernel<<<528, 256, 0, stream>>>(x, Wc, bc, Hb, W5, W5h, W5l);

    if (batched) {
        // ---- stage 1: C=2, O=64 ----
        gram_small_kernel<<<dim3(32, 32, 2), 256, 0, stream>>>(Hb, (long)N_PTS * 2, NST, NEGD);
        topk_kernel<1><<<dim3(N_PTS, 2), 256, 0, stream>>>(NEGD, NST, IDX);
        ya_z_kernel<2, 64, 1><<<dim3(128, 1, BATCH), 256, 0, stream>>>(Hb, 2, (long)N_PTS * 2,
                                                                       W1, b1, YaT, ZT);
        edge_reduce_kernel<64, 1, 1><<<dim3(128, BATCH), 256, 0, stream>>>(YaT, ZT, IDX, CAT,
                                                                           CATh, CATl, XX, 0);
        // ---- stage 2: C=64 (slice 0:64), O=64 ----
        gram_mfma_kernel<64, 2><<<dim3(16, 32, 2), 256, 0, stream>>>(
            CATh + 0, CATl + 0, (long)N_PTS * 512, 512, XX, N_PTS, NEGD, NST);
        topk_kernel<2><<<dim3(N_PTS, 2), 256, 0, stream>>>(NEGD, NST, IDX);
        ya_z_kernel<64, 64, 2><<<dim3(128, 1, BATCH), 256, 0, stream>>>(CAT + 0, 512,
                                                                        (long)N_PTS * 512,
                                                                        W2, b2, YaT, ZT);
        edge_reduce_kernel<64, 2, 1><<<dim3(128, BATCH), 256, 0, stream>>>(YaT, ZT, IDX, CAT,
                                                                           CATh, CATl, XX, 64);
        // ---- stage 3: C=64 (slice 64:128), O=128 ----
        gram_mfma_kernel<64, 3><<<dim3(16, 32, 2), 256, 0, stream>>>(
            CATh + 64, CATl + 64, (long)N_PTS * 512, 512, XX, N_PTS, NEGD, NST);
        topk_kernel<3><<<dim3(N_PTS, 2), 256, 0, stream>>>(NEGD, NST, IDX);
        ya_z_kernel<64, 128, 3><<<dim3(128, 2, BATCH), 256, 0, stream>>>(CAT + 64, 512,
                                                                         (long)N_PTS * 512,
                                                                         W3, b3, YaT, ZT);
        edge_reduce_kernel<128, 3, 1><<<dim3(256, BATCH), 256, 0, stream>>>(YaT, ZT, IDX, CAT,
                                                                            CATh, CATl, XX, 128);
        // ---- stage 4: C=128 (slice 128:256), O=256 ----
        gram_mfma_kernel<128, 4><<<dim3(16, 32, 2), 256, 0, stream>>>(
            CATh + 128, CATl + 128, (long)N_PTS * 512, 512, XX, N_PTS, NEGD, NST);
        topk_kernel<4><<<dim3(N_PTS, 2), 256, 0, stream>>>(NEGD, NST, IDX);
        ya_z_kernel<128, 256, 4><<<dim3(128, 4, BATCH), 256, 0, stream>>>(CAT + 128, 512,
                                                                          (long)N_PTS * 512,
                                                                          W4, b4, YaT, ZT);
        edge_reduce_kernel<256, 4, 0><<<dim3(512, BATCH), 256, 0, stream>>>(YaT, ZT, IDX, CAT,
                                                                            CATh, CATl, XX, 256);
    } else {
        // fallback: sequential per-batch (NEGD holds one batch)
        for (int b = 0; b < BATCH; ++b) {
            gram_small_kernel<<<dim3(32, 32, 1), 256, 0, stream>>>(Hb + (size_t)b * N_PTS * 2, 0,
                                                                   0, NEGD);
            topk_kernel<1><<<dim3(N_PTS, 1), 256, 0, stream>>>(NEGD, 0,
                                                               IDX + (size_t)b * N_PTS * KNN);
        }
        ya_z_kernel<2, 64, 1><<<dim3(128, 1, BATCH), 256, 0, stream>>>(Hb, 2, (long)N_PTS * 2,
                                                                       W1, b1, YaT, ZT);
        edge_reduce_kernel<64, 1, 1><<<dim3(128, BATCH), 256, 0, stream>>>(YaT, ZT, IDX, CAT,
                                                                           CATh, CATl, XX, 0);
        for (int b = 0; b < BATCH; ++b) {
            gram_mfma_kernel<64, 2><<<dim3(16, 32, 1), 256, 0, stream>>>(
                CATh + 0 + (size_t)b * N_PTS * 512, CATl + 0 + (size_t)b * N_PTS * 512, 0, 512,
                XX + b * N_PTS, 0, NEGD, 0);
            topk_kernel<2><<<dim3(N_PTS, 1), 256, 0, stream>>>(NEGD, 0,
                                                               IDX + (size_t)b * N_PTS * KNN);
        }
        ya_z_kernel<64, 64, 2><<<dim3(128, 1, BATCH), 256, 0, stream>>>(CAT + 0, 512,
                                                                        (long)N_PTS * 512,
                                                                        W2, b2, YaT, ZT);
        edge_reduce_kernel<64, 2, 1><<<dim3(128, BATCH), 256, 0, stream>>>(YaT, ZT, IDX, CAT,
                                                                           CATh, CATl, XX, 64);
        for (int b = 0; b < BATCH; ++b) {
            gram_mfma_kernel<64, 3><<<dim3(16, 32, 1), 256, 0, stream>>>(
                CATh + 64 + (size_t)b * N_PTS * 512, CATl + 64 + (size_t)b * N_PTS * 512, 0, 512,
                XX + b * N_PTS, 0, NEGD, 0);
            topk_kernel<3><<<dim3(N_PTS, 1), 256, 0, stream>>>(NEGD, 0,
                                                               IDX + (size_t)b * N_PTS * KNN);
        }
        ya_z_kernel<64, 128, 3><<<dim3(128, 2, BATCH), 256, 0, stream>>>(CAT + 64, 512,
                                                                         (long)N_PTS * 512,
                                                                         W3, b3, YaT, ZT);
        edge_reduce_kernel<128, 3, 1><<<dim3(256, BATCH), 256, 0, stream>>>(YaT, ZT, IDX, CAT,
                                                                            CATh, CATl, XX, 128);
        for (int b = 0; b < BATCH; ++b) {
            gram_mfma_kernel<128, 4><<<dim3(16, 32, 1), 256, 0, stream>>>(
                CATh + 128 + (size_t)b * N_PTS * 512, CATl + 128 + (size_t)b * N_PTS * 512, 0, 512,
                XX + b * N_PTS, 0, NEGD, 0);
            topk_kernel<4><<<dim3(N_PTS, 1), 256, 0, stream>>>(NEGD, 0,
                                                               IDX + (size_t)b * N_PTS * KNN);
        }
        ya_z_kernel<128, 256, 4><<<dim3(128, 4, BATCH), 256, 0, stream>>>(CAT + 128, 512,
                                                                          (long)N_PTS * 512,
                                                                          W4, b4, YaT, ZT);
        edge_reduce_kernel<256, 4, 0><<<dim3(512, BATCH), 256, 0, stream>>>(YaT, ZT, IDX, CAT,
                                                                            CATh, CATl, XX, 256);
    }

    // ---- global feature: W5 MFMA + max (W5h/W5l prepared at start) ----
    w5max_mfma_kernel<<<dim3(16, 8, BATCH), 256, 0, stream>>>(CATh, CATl, W5h, W5l, b5, PART);
    greduce_kernel<<<8, 256, 0, stream>>>(PART, G);
    fc_kernel<<<4096, 256, 0, stream>>>(G, Wfc, bfc, D0);

    // ---- decoder: quad upconvs ----
    upconv_quad_kernel<64, 32, 16, 16, 1><<<dim3(1, 32, BATCH), 256, 0, stream>>>(D0, Wd1, bd1,
                                                                                  DEC1);
    upconv_quad_kernel<32, 16, 32, 32, 1><<<dim3(4, 16, BATCH), 256, 0, stream>>>(DEC1, Wd2, bd2,
                                                                                  DEC2);
    upconv_quad_kernel<16, 1, 64, 64, 0><<<dim3(16, 1, BATCH), 256, 0, stream>>>(DEC2, Wd3, bd3,
                                                                                 out);
}

// Round 17
// 346.106 us; speedup vs baseline: 1.0238x; 1.0238x over previous
//
#include <hip/hip_runtime.h>
#include <hip/hip_bf16.h>

#define N_PTS 2048
#define BATCH 2
#define KNN 40

typedef __attribute__((ext_vector_type(8))) short bf16x8;
typedef __attribute__((ext_vector_type(16))) float f32x16;

__device__ __forceinline__ float lrelu(float v, float s) {
    return v >= 0.f ? v : s * v;
}

// ---------------- prefix body: conv (5,3)/(5,1) + lrelu(0.01) -> H (B,N,2) --------------
__device__ __forceinline__ void prefix_body(int fb, const float* __restrict__ x,
                                            const float* __restrict__ Wc,
                                            const float* __restrict__ bc,
                                            float* __restrict__ H) {
    int t = fb * 256 + threadIdx.x;
    if (t >= BATCH * N_PTS) return;
    int b = t >> 11, n = t & 2047;
    #pragma unroll
    for (int oh = 0; oh < 2; ++oh) {
        float acc = bc[0];
        #pragma unroll
        for (int kh = 0; kh < 5; ++kh) {
            const float* xr = x + ((size_t)b * 10 + oh * 5 + kh) * N_PTS;
            #pragma unroll
            for (int kw = 0; kw < 3; ++kw) {
                int nn = n + kw - 1;
                if (nn >= 0 && nn < N_PTS) acc += xr[nn] * Wc[kh * 3 + kw];
            }
        }
        H[(size_t)t * 2 + oh] = lrelu(acc, 0.01f);
    }
}

// ---------------- cvt body: fp32 -> bf16 hi/lo split (contiguous) ----------------
__device__ __forceinline__ void cvt_body(int t, const float* __restrict__ src,
                                         short* __restrict__ hi, short* __restrict__ lo,
                                         int total4) {
    if (t >= total4) return;
    float4 v = ((const float4*)src)[t];
    short4 h, l;
    #pragma unroll
    for (int j = 0; j < 4; ++j) {
        float xv = (&v.x)[j];
        __hip_bfloat16 hb = __float2bfloat16(xv);
        float hf = __bfloat162float(hb);
        __hip_bfloat16 lb = __float2bfloat16(xv - hf);
        (&h.x)[j] = *reinterpret_cast<short*>(&hb);
        (&l.x)[j] = *reinterpret_cast<short*>(&lb);
    }
    ((short4*)hi)[t] = h;
    ((short4*)lo)[t] = l;
}

// ---------------- prefix + W5 split co-launch (both depend only on inputs) --------------
__global__ __launch_bounds__(256) void prefix_cvt_kernel(const float* __restrict__ x,
                                                         const float* __restrict__ Wc,
                                                         const float* __restrict__ bc,
                                                         float* __restrict__ H,
                                                         const float* __restrict__ W5,
                                                         short* __restrict__ W5h,
                                                         short* __restrict__ W5l) {
    int fb = blockIdx.x;
    if (fb < 16) prefix_body(fb, x, Wc, bc, H);
    else cvt_body((fb - 16) * 256 + threadIdx.x, W5, W5h, W5l, 1024 * 512 / 4);
}

// ---------------- gram small (C=2, stage 1): 64x64 tile, fused xx, fp32 ----------------
__global__ __launch_bounds__(256) void gram_small_kernel(const float* __restrict__ X, long bsX,
                                                         long nstride,
                                                         float* __restrict__ negd) {
    __shared__ float AsT[2][68];
    __shared__ float BsT[2][68];
    __shared__ float xxr[64];
    __shared__ float xxc[64];
    int bz = blockIdx.z;
    const float* Xb = X + (size_t)bz * bsX;
    float* nd = negd + (size_t)bz * nstride;
    int tid = threadIdx.x;
    int r0 = blockIdx.y * 64, c0 = blockIdx.x * 64;
    int ty = tid >> 4, tx = tid & 15;
    if (tid < 128) {
        int r = tid >> 1, c = tid & 1;
        AsT[c][r] = Xb[(size_t)(r0 + r) * 2 + c];
        BsT[c][r] = Xb[(size_t)(c0 + r) * 2 + c];
        int v = (tid < 64) ? (r0 + tid) : (c0 + tid - 64);
        float x0 = Xb[(size_t)v * 2], x1 = Xb[(size_t)v * 2 + 1];
        float s = 0.f;
        s += x0 * x0;
        s += x1 * x1;
        if (tid < 64) xxr[tid] = s; else xxc[tid - 64] = s;
    }
    __syncthreads();
    float acc[4][4] = {};
    #pragma unroll
    for (int k = 0; k < 2; ++k) {
        float4 a = *(const float4*)&AsT[k][ty * 4];
        float4 b = *(const float4*)&BsT[k][tx * 4];
        #pragma unroll
        for (int i = 0; i < 4; ++i)
            #pragma unroll
            for (int j = 0; j < 4; ++j)
                acc[i][j] += (&a.x)[i] * (&b.x)[j];
    }
    #pragma unroll
    for (int i = 0; i < 4; ++i) {
        int r = r0 + ty * 4 + i;
        float xr = xxr[ty * 4 + i];
        #pragma unroll
        for (int j = 0; j < 4; ++j) {
            int c = c0 + tx * 4 + j;
            nd[(size_t)r * N_PTS + c] = 2.0f * acc[i][j] - xr - xxc[tx * 4 + j];
        }
    }
}

// ---------------- gram MFMA (C=64/128): split-bf16 3-pass, 128x128 block, L2-direct -----
// round-13 body: 4 independent acc chains, register double-buffer. grid (16,16,B).
template<int C, int STAGE>
__global__ __launch_bounds__(256) void gram_mfma_kernel(
        const short* __restrict__ Xh, const short* __restrict__ Xl, long bsX, int S,
        const float* __restrict__ xx, long xxstride,
        float* __restrict__ negd, long nstride) {
    constexpr int NCH = C / 16;
    __shared__ float xr_s[128];
    __shared__ float xc_s[128];
    int bz = blockIdx.z;
    const short* Ah = Xh + (size_t)bz * bsX;
    const short* Al = Xl + (size_t)bz * bsX;
    const float* xxb = xx + (size_t)bz * xxstride;
    float* nd = negd + (size_t)bz * nstride;
    int tid = threadIdx.x;
    int wave = tid >> 6, lane = tid & 63;
    int wm = wave >> 1, wn = wave & 1;
    int r0 = blockIdx.y * 128 + wm * 64;
    int c0 = blockIdx.x * 128 + wn * 64;
    int rr = lane & 31, kg = lane >> 5;
    if (tid < 128) xr_s[tid] = xxb[blockIdx.y * 128 + tid];
    else           xc_s[tid - 128] = xxb[blockIdx.x * 128 + (tid - 128)];
    const int FS = 32 * S;
    const short* pAh = Ah + (size_t)(r0 + rr) * S + kg * 8;
    const short* pAl = Al + (size_t)(r0 + rr) * S + kg * 8;
    const short* pBh = Ah + (size_t)(c0 + rr) * S + kg * 8;
    const short* pBl = Al + (size_t)(c0 + rr) * S + kg * 8;
    f32x16 a00 = {}, a01 = {}, a10 = {}, a11 = {};
    bf16x8 ah0 = *(const bf16x8*)(pAh);
    bf16x8 ah1 = *(const bf16x8*)(pAh + FS);
    bf16x8 al0 = *(const bf16x8*)(pAl);
    bf16x8 al1 = *(const bf16x8*)(pAl + FS);
    bf16x8 bh0 = *(const bf16x8*)(pBh);
    bf16x8 bh1 = *(const bf16x8*)(pBh + FS);
    bf16x8 bl0 = *(const bf16x8*)(pBl);
    bf16x8 bl1 = *(const bf16x8*)(pBl + FS);
    #pragma unroll 2
    for (int kc = 0; kc < NCH; ++kc) {
        int kn = ((kc + 1) & (NCH - 1)) * 16;
        bf16x8 nah0 = *(const bf16x8*)(pAh + kn);
        bf16x8 nah1 = *(const bf16x8*)(pAh + kn + FS);
        bf16x8 nal0 = *(const bf16x8*)(pAl + kn);
        bf16x8 nal1 = *(const bf16x8*)(pAl + kn + FS);
        bf16x8 nbh0 = *(const bf16x8*)(pBh + kn);
        bf16x8 nbh1 = *(const bf16x8*)(pBh + kn + FS);
        bf16x8 nbl0 = *(const bf16x8*)(pBl + kn);
        bf16x8 nbl1 = *(const bf16x8*)(pBl + kn + FS);
        a00 = __builtin_amdgcn_mfma_f32_32x32x16_bf16(ah0, bh0, a00, 0, 0, 0);
        a00 = __builtin_amdgcn_mfma_f32_32x32x16_bf16(ah0, bl0, a00, 0, 0, 0);
        a00 = __builtin_amdgcn_mfma_f32_32x32x16_bf16(al0, bh0, a00, 0, 0, 0);
        a01 = __builtin_amdgcn_mfma_f32_32x32x16_bf16(ah0, bh1, a01, 0, 0, 0);
        a01 = __builtin_amdgcn_mfma_f32_32x32x16_bf16(ah0, bl1, a01, 0, 0, 0);
        a01 = __builtin_amdgcn_mfma_f32_32x32x16_bf16(al0, bh1, a01, 0, 0, 0);
        a10 = __builtin_amdgcn_mfma_f32_32x32x16_bf16(ah1, bh0, a10, 0, 0, 0);
        a10 = __builtin_amdgcn_mfma_f32_32x32x16_bf16(ah1, bl0, a10, 0, 0, 0);
        a10 = __builtin_amdgcn_mfma_f32_32x32x16_bf16(al1, bh0, a10, 0, 0, 0);
        a11 = __builtin_amdgcn_mfma_f32_32x32x16_bf16(ah1, bh1, a11, 0, 0, 0);
        a11 = __builtin_amdgcn_mfma_f32_32x32x16_bf16(ah1, bl1, a11, 0, 0, 0);
        a11 = __builtin_amdgcn_mfma_f32_32x32x16_bf16(al1, bh1, a11, 0, 0, 0);
        ah0 = nah0; ah1 = nah1; al0 = nal0; al1 = nal1;
        bh0 = nbh0; bh1 = nbh1; bl0 = nbl0; bl1 = nbl1;
    }
    __syncthreads();
    int colF = lane & 31;
    int hi4 = (lane >> 5) * 4;
    #pragma unroll
    for (int f = 0; f < 4; ++f) {
        int fm = f >> 1, fn = f & 1;
        int cIn = wn * 64 + fn * 32 + colF;
        float xc = xc_s[cIn];
        float* ndr = nd + (size_t)(blockIdx.y * 128) * N_PTS + blockIdx.x * 128 + cIn;
        #pragma unroll
        for (int reg = 0; reg < 16; ++reg) {
            float av = (f == 0) ? a00[reg] : (f == 1) ? a01[reg] : (f == 2) ? a10[reg] : a11[reg];
            int rIn = wm * 64 + fm * 32 + (reg & 3) + 8 * (reg >> 2) + hi4;
            ndr[(size_t)rIn * N_PTS] = 2.0f * av - xr_s[rIn] - xc;
        }
    }
}

// ---------------- top-40 per row: single-pass radix select (11/11/10 bits) ---------------
template<int STAGE>
__global__ __launch_bounds__(256) void topk_kernel(const float* __restrict__ negd, long nstride,
                                                   int* __restrict__ idx_out) {
    __shared__ unsigned hist[2048];
    __shared__ unsigned cand[2048];
    __shared__ unsigned wsum[4];
    __shared__ unsigned sc[4];
    __shared__ unsigned tieb;
    int bz = blockIdx.y;
    int n = blockIdx.x;
    int tid = threadIdx.x;
    int wave = tid >> 6, lane = tid & 63;
    const float* row = negd + (size_t)bz * nstride + (size_t)n * N_PTS;
    float4 v0 = ((const float4*)row)[tid];
    float4 v1 = ((const float4*)row)[tid + 256];
    unsigned k0[4], k1[4];
    #pragma unroll
    for (int e = 0; e < 4; ++e) {
        unsigned u = __float_as_uint((&v0.x)[e]);
        k0[e] = (u & 0x80000000u) ? ~u : (u | 0x80000000u);
        u = __float_as_uint((&v1.x)[e]);
        k1[e] = (u & 0x80000000u) ? ~u : (u | 0x80000000u);
    }
    for (int i = tid; i < 2048; i += 256) hist[i] = 0u;
    if (tid == 0) { sc[2] = 0u; sc[3] = 0u; }
    __syncthreads();
    #pragma unroll
    for (int e = 0; e < 4; ++e) {
        atomicAdd(&hist[k0[e] >> 21], 1u);
        atomicAdd(&hist[k1[e] >> 21], 1u);
    }
    __syncthreads();
    unsigned r = KNN;
    {
        unsigned chunk = 0;
        #pragma unroll
        for (int q = 0; q < 8; ++q) chunk += hist[tid * 8 + q];
        unsigned s = chunk;
        #pragma unroll
        for (int off = 1; off < 64; off <<= 1) {
            unsigned v = __shfl_down(s, off);
            if (lane + off < 64) s += v;
        }
        if (lane == 0) wsum[wave] = s;
        __syncthreads();
        unsigned add = 0;
        for (int w = wave + 1; w < 4; ++w) add += wsum[w];
        unsigned St = s + add, Sn = St - chunk;
        if (St >= r && Sn < r) { sc[0] = (unsigned)tid; sc[1] = r - Sn; }
        __syncthreads();
        if (tid == 0) {
            int c = (int)sc[0]; unsigned rc = sc[1];
            unsigned cum = 0; int b = c * 8 + 7;
            for (;; --b) { cum += hist[b]; if (cum >= rc) break; }
            sc[0] = (unsigned)b; sc[1] = rc - (cum - hist[b]);
        }
        __syncthreads();
    }
    unsigned p1 = sc[0]; r = sc[1];
    __syncthreads();
    for (int i = tid; i < 2048; i += 256) hist[i] = 0u;
    __syncthreads();
    int* out = idx_out + ((size_t)bz * N_PTS + n) * KNN;
    #pragma unroll
    for (int h = 0; h < 2; ++h) {
        #pragma unroll
        for (int e = 0; e < 4; ++e) {
            unsigned u = (h == 0) ? k0[e] : k1[e];
            int j = (tid + h * 256) * 4 + e;
            unsigned b = u >> 21;
            if (b > p1) {
                out[atomicAdd(&sc[2], 1u)] = j;
            } else if (b == p1) {
                unsigned low = u & 0x1FFFFFu;
                cand[atomicAdd(&sc[3], 1u)] = (low << 11) | (unsigned)j;
                atomicAdd(&hist[low >> 10], 1u);
            }
        }
    }
    __syncthreads();
    int cnt = (int)sc[3];
    {
        unsigned chunk = 0;
        #pragma unroll
        for (int q = 0; q < 8; ++q) chunk += hist[tid * 8 + q];
        unsigned s = chunk;
        #pragma unroll
        for (int off = 1; off < 64; off <<= 1) {
            unsigned v = __shfl_down(s, off);
            if (lane + off < 64) s += v;
        }
        if (lane == 0) wsum[wave] = s;
        __syncthreads();
        unsigned add = 0;
        for (int w = wave + 1; w < 4; ++w) add += wsum[w];
        unsigned St = s + add, Sn = St - chunk;
        if (St >= r && Sn < r) { sc[0] = (unsigned)tid; sc[1] = r - Sn; }
        __syncthreads();
        if (tid == 0) {
            int c = (int)sc[0]; unsigned rc = sc[1];
            unsigned cum = 0; int b = c * 8 + 7;
            for (;; --b) { cum += hist[b]; if (cum >= rc) break; }
            sc[0] = (unsigned)b; sc[1] = rc - (cum - hist[b]);
        }
        __syncthreads();
    }
    unsigned b2 = sc[0]; r = sc[1];
    __syncthreads();
    for (int i = tid; i < 1024; i += 256) hist[i] = 0u;
    __syncthreads();
    for (int i = tid; i < cnt; i += 256) {
        unsigned p = cand[i];
        if ((p >> 21) == b2) atomicAdd(&hist[(p >> 11) & 0x3FFu], 1u);
    }
    __syncthreads();
    {
        unsigned chunk = 0;
        #pragma unroll
        for (int q = 0; q < 4; ++q) chunk += hist[tid * 4 + q];
        unsigned s = chunk;
        #pragma unroll
        for (int off = 1; off < 64; off <<= 1) {
            unsigned v = __shfl_down(s, off);
            if (lane + off < 64) s += v;
        }
        if (lane == 0) wsum[wave] = s;
        __syncthreads();
        unsigned add = 0;
        for (int w = wave + 1; w < 4; ++w) add += wsum[w];
        unsigned St = s + add, Sn = St - chunk;
        if (St >= r && Sn < r) { sc[0] = (unsigned)tid; sc[1] = r - Sn; }
        __syncthreads();
        if (tid == 0) {
            int c = (int)sc[0]; unsigned rc = sc[1];
            unsigned cum = 0; int b = c * 4 + 3;
            for (;; --b) { cum += hist[b]; if (cum >= rc) break; }
            sc[0] = (unsigned)b; sc[1] = rc - (cum - hist[b]);
        }
        __syncthreads();
    }
    unsigned Tlow = (b2 << 10) | sc[0];
    unsigned r3 = sc[1];
    __syncthreads();
    for (int i = tid; i < cnt; i += 256) {
        unsigned p = cand[i];
        if ((p >> 11) > Tlow) out[atomicAdd(&sc[2], 1u)] = (int)(p & 0x7FFu);
    }
    __syncthreads();
    int last = -1;
    for (unsigned t = 0; t < r3; ++t) {
        unsigned m = 0xFFFFFFFFu;
        for (int i = tid; i < cnt; i += 256) {
            unsigned p = cand[i];
            if ((p >> 11) == Tlow) {
                int j = (int)(p & 0x7FFu);
                if (j > last && (unsigned)j < m) m = (unsigned)j;
            }
        }
        hist[tid] = m;
        __syncthreads();
        for (int st = 128; st >= 1; st >>= 1) {
            if (tid < st) hist[tid] = min(hist[tid], hist[tid + st]);
            __syncthreads();
        }
        if (tid == 0) { out[KNN - (int)r3 + (int)t] = (int)hist[0]; tieb = hist[0]; }
        __syncthreads();
        last = (int)tieb;
    }
}

// ---------------- YaT = X @ Wa^T ; ZT = X @ Wb^T - YaT + bias  (layout (B,N,O)) ---------
template<int C, int O, int STAGE>
__global__ __launch_bounds__(256) void ya_z_kernel(const float* __restrict__ X, int S, long bsX,
                                                   const float* __restrict__ W,
                                                   const float* __restrict__ bias,
                                                   float* __restrict__ YaT, float* __restrict__ ZT) {
    constexpr int KC = (C < 32) ? C : 32;
    __shared__ float Xs[16][KC + 1];
    __shared__ float WaS[KC][64];
    __shared__ float WbS[KC][64];
    int b = blockIdx.z;
    const float* Xb = X + (size_t)b * bsX;
    int n0 = blockIdx.x * 16, o0 = blockIdx.y * 64;
    int tid = threadIdx.x, ty = tid >> 4, tx = tid & 15;
    float aa[4] = {}, ab[4] = {};
    for (int k0 = 0; k0 < C; k0 += KC) {
        __syncthreads();
        for (int i = tid; i < 16 * KC; i += 256) {
            int rw = i / KC, c = i % KC;
            Xs[rw][c] = Xb[(size_t)(n0 + rw) * S + k0 + c];
        }
        for (int i = tid; i < 64 * KC; i += 256) {
            int rw = i / KC, c = i % KC;
            int scol = rw ^ ((c & 15) << 2);
            WaS[c][scol] = W[(size_t)(o0 + rw) * 2 * C + k0 + c];
            WbS[c][scol] = W[(size_t)(o0 + rw) * 2 * C + C + k0 + c];
        }
        __syncthreads();
        #pragma unroll
        for (int k = 0; k < KC; ++k) {
            float xv = Xs[ty][k];
            int m = (k & 15) << 2;
            float4 wa = *(const float4*)&WaS[k][(tx * 4) ^ m];
            float4 wb = *(const float4*)&WbS[k][(tx * 4) ^ m];
            #pragma unroll
            for (int j = 0; j < 4; ++j) {
                aa[j] += xv * (&wa.x)[j];
                ab[j] += xv * (&wb.x)[j];
            }
        }
    }
    int n = n0 + ty;
    float4 ya, zt;
    #pragma unroll
    for (int j = 0; j < 4; ++j) {
        int o = o0 + tx * 4 + j;
        (&ya.x)[j] = aa[j];
        (&zt.x)[j] = ab[j] - aa[j] + bias[o];
    }
    size_t off = ((size_t)b * N_PTS + n) * O + o0 + tx * 4;
    *(float4*)&YaT[off] = ya;
    *(float4*)&ZT[off] = zt;
}

// ---------------- edge reduce (vectorized x4) + fused bf16-split + xx for next stage ----
template<int O, int STAGE, int AUX>
__global__ __launch_bounds__(256) void edge_reduce_kernel(const float* __restrict__ YaT,
                                                          const float* __restrict__ ZT,
                                                          const int* __restrict__ IDX,
                                                          float* __restrict__ CATp,
                                                          short* __restrict__ CATh,
                                                          short* __restrict__ CATl,
                                                          float* __restrict__ XX, int coloff) {
    constexpr int TPR = O / 4;           // threads per row
    int b = blockIdx.y;
    int tid = threadIdx.x;
    int n = blockIdx.x * (256 / TPR) + tid / TPR;
    int o = (tid % TPR) * 4;
    const float* Ya_b = YaT + (size_t)b * N_PTS * O;
    size_t rowoff = (size_t)b * N_PTS + n;
    float4 z = *(const float4*)&ZT[rowoff * O + o];
    const int* ir = IDX + rowoff * KNN;
    float4 acc = {-3.4e38f, -3.4e38f, -3.4e38f, -3.4e38f};
    #pragma unroll 8
    for (int k = 0; k < KNN; ++k) {
        int m = ir[k];
        float4 v = *(const float4*)&Ya_b[(size_t)m * O + o];
        acc.x = fmaxf(acc.x, lrelu(v.x + z.x, 0.2f));
        acc.y = fmaxf(acc.y, lrelu(v.y + z.y, 0.2f));
        acc.z = fmaxf(acc.z, lrelu(v.z + z.z, 0.2f));
        acc.w = fmaxf(acc.w, lrelu(v.w + z.w, 0.2f));
    }
    size_t coff = rowoff * 512 + coloff + o;
    *(float4*)&CATp[coff] = acc;
    short4 h, l;
    #pragma unroll
    for (int j = 0; j < 4; ++j) {
        float xv = (&acc.x)[j];
        __hip_bfloat16 hb = __float2bfloat16(xv);
        float hf = __bfloat162float(hb);
        __hip_bfloat16 lb = __float2bfloat16(xv - hf);
        (&h.x)[j] = *reinterpret_cast<short*>(&hb);
        (&l.x)[j] = *reinterpret_cast<short*>(&lb);
    }
    *(short4*)&CATh[coff] = h;
    *(short4*)&CATl[coff] = l;
    if (AUX) {
        float sq = acc.x * acc.x + acc.y * acc.y + acc.z * acc.z + acc.w * acc.w;
        #pragma unroll
        for (int off = 1; off < TPR; off <<= 1) sq += __shfl_xor(sq, off);
        if ((tid % TPR) == 0) XX[rowoff] = sq;
    }
}

// ---------------- w5max: split-bf16 3-pass MFMA, L2-direct ----------------
__global__ __launch_bounds__(256) void w5max_mfma_kernel(
        const short* __restrict__ Ah, const short* __restrict__ Al,
        const short* __restrict__ Bh, const short* __restrict__ Bl,
        const float* __restrict__ b5, float* __restrict__ PART) {
    __shared__ float red[2][128];
    int b = blockIdx.z;
    int tid = threadIdx.x;
    int wave = tid >> 6, lane = tid & 63;
    int wm = wave >> 1, wn = wave & 1;
    int m0 = blockIdx.x * 128 + wm * 64;
    int o0 = blockIdx.y * 128 + wn * 64;
    int rr = lane & 31;
    int kg = lane >> 5;
    const int FS = 32 * 512;
    const short* pAh = Ah + ((size_t)b * N_PTS + m0 + rr) * 512 + kg * 8;
    const short* pAl = Al + ((size_t)b * N_PTS + m0 + rr) * 512 + kg * 8;
    const short* pBh = Bh + (size_t)(o0 + rr) * 512 + kg * 8;
    const short* pBl = Bl + (size_t)(o0 + rr) * 512 + kg * 8;
    f32x16 a00 = {}, a01 = {}, a10 = {}, a11 = {};
    bf16x8 ah0 = *(const bf16x8*)(pAh);
    bf16x8 ah1 = *(const bf16x8*)(pAh + FS);
    bf16x8 al0 = *(const bf16x8*)(pAl);
    bf16x8 al1 = *(const bf16x8*)(pAl + FS);
    bf16x8 bh0 = *(const bf16x8*)(pBh);
    bf16x8 bh1 = *(const bf16x8*)(pBh + FS);
    bf16x8 bl0 = *(const bf16x8*)(pBl);
    bf16x8 bl1 = *(const bf16x8*)(pBl + FS);
    #pragma unroll 2
    for (int kc = 0; kc < 32; ++kc) {
        int kn = ((kc + 1) & 31) * 16;
        bf16x8 nah0 = *(const bf16x8*)(pAh + kn);
        bf16x8 nah1 = *(const bf16x8*)(pAh + kn + FS);
        bf16x8 nal0 = *(const bf16x8*)(pAl + kn);
        bf16x8 nal1 = *(const bf16x8*)(pAl + kn + FS);
        bf16x8 nbh0 = *(const bf16x8*)(pBh + kn);
        bf16x8 nbh1 = *(const bf16x8*)(pBh + kn + FS);
        bf16x8 nbl0 = *(const bf16x8*)(pBl + kn);
        bf16x8 nbl1 = *(const bf16x8*)(pBl + kn + FS);
        a00 = __builtin_amdgcn_mfma_f32_32x32x16_bf16(ah0, bh0, a00, 0, 0, 0);
        a00 = __builtin_amdgcn_mfma_f32_32x32x16_bf16(ah0, bl0, a00, 0, 0, 0);
        a00 = __builtin_amdgcn_mfma_f32_32x32x16_bf16(al0, bh0, a00, 0, 0, 0);
        a01 = __builtin_amdgcn_mfma_f32_32x32x16_bf16(ah0, bh1, a01, 0, 0, 0);
        a01 = __builtin_amdgcn_mfma_f32_32x32x16_bf16(ah0, bl1, a01, 0, 0, 0);
        a01 = __builtin_amdgcn_mfma_f32_32x32x16_bf16(al0, bh1, a01, 0, 0, 0);
        a10 = __builtin_amdgcn_mfma_f32_32x32x16_bf16(ah1, bh0, a10, 0, 0, 0);
        a10 = __builtin_amdgcn_mfma_f32_32x32x16_bf16(ah1, bl0, a10, 0, 0, 0);
        a10 = __builtin_amdgcn_mfma_f32_32x32x16_bf16(al1, bh0, a10, 0, 0, 0);
        a11 = __builtin_amdgcn_mfma_f32_32x32x16_bf16(ah1, bh1, a11, 0, 0, 0);
        a11 = __builtin_amdgcn_mfma_f32_32x32x16_bf16(ah1, bl1, a11, 0, 0, 0);
        a11 = __builtin_amdgcn_mfma_f32_32x32x16_bf16(al1, bh1, a11, 0, 0, 0);
        ah0 = nah0; ah1 = nah1; al0 = nal0; al1 = nal1;
        bh0 = nbh0; bh1 = nbh1; bl0 = nbl0; bl1 = nbl1;
    }
    #pragma unroll
    for (int fn = 0; fn < 2; ++fn) {
        float bo = b5[o0 + fn * 32 + rr];
        float m = -3.4e38f;
        #pragma unroll
        for (int r = 0; r < 16; ++r) {
            float v0 = (fn == 0) ? a00[r] : a01[r];
            float v1 = (fn == 0) ? a10[r] : a11[r];
            m = fmaxf(m, lrelu(v0 + bo, 0.2f));
            m = fmaxf(m, lrelu(v1 + bo, 0.2f));
        }
        m = fmaxf(m, __shfl_xor(m, 32));
        red[wm][wn * 64 + fn * 32 + rr] = m;
    }
    __syncthreads();
    if (tid < 128)
        PART[((size_t)b * 16 + blockIdx.x) * 1024 + blockIdx.y * 128 + tid] =
            fmaxf(red[0][tid], red[1][tid]);
}

__global__ void greduce_kernel(const float* __restrict__ PART, float* __restrict__ G) {
    int t = blockIdx.x * 256 + threadIdx.x;
    if (t >= BATCH * 1024) return;
    int b = t >> 10, o = t & 1023;
    const float* p = PART + (size_t)b * 16 * 1024 + o;
    float m = -3.4e38f;
    for (int nb = 0; nb < 16; ++nb) m = fmaxf(m, p[(size_t)nb * 1024]);
    G[t] = m;
}

// ---------------- FC: D0[b,j] = lrelu(g[b,:] . Wfc[j,:] + bfc[j]) ----------------
__global__ __launch_bounds__(256) void fc_kernel(const float* __restrict__ G,
                                                 const float* __restrict__ Wfc,
                                                 const float* __restrict__ bfc,
                                                 float* __restrict__ D0) {
    __shared__ float gl[2][1024];
    int tid = threadIdx.x;
    for (int i = tid; i < 2048; i += 256) gl[i >> 10][i & 1023] = G[i];
    __syncthreads();
    int wave = tid >> 6, lane = tid & 63;
    int j = blockIdx.x * 4 + wave;
    const float* wr = Wfc + (size_t)j * 1024;
    float a0 = 0.f, a1 = 0.f;
    for (int i = lane; i < 1024; i += 64) {
        float w = wr[i];
        a0 += w * gl[0][i];
        a1 += w * gl[1][i];
    }
    #pragma unroll
    for (int off = 32; off; off >>= 1) { a0 += __shfl_xor(a0, off); a1 += __shfl_xor(a1, off); }
    if (lane == 0) {
        float bb = bfc[j];
        D0[j] = lrelu(a0 + bb, 0.2f);
        D0[16384 + j] = lrelu(a1 + bb, 0.2f);
    }
}

// ---------------- fused up2 + conv3x3: quad kernel ----------------
template<int CI, int CO, int HI, int WI, int RELU>
__global__ __launch_bounds__(256) void upconv_quad_kernel(const float* __restrict__ in,
                                                          const float* __restrict__ W,
                                                          const float* __restrict__ bias,
                                                          float* __restrict__ out) {
    const int qid = blockIdx.x * 256 + threadIdx.x;
    const int p = qid / WI, q = qid % WI;
    const int co = blockIdx.y, b = blockIdx.z;
    const int HO = HI * 2, WO = WI * 2;
    int off[3][3];
    float msk[3][3];
    #pragma unroll
    for (int r = 0; r < 3; ++r) {
        int pr = p - 1 + r;
        float rm = (pr >= 0 && pr < HI) ? 1.f : 0.f;
        int prc = min(max(pr, 0), HI - 1);
        #pragma unroll
        for (int c = 0; c < 3; ++c) {
            int qc = q - 1 + c;
            float cm = (qc >= 0 && qc < WI) ? 1.f : 0.f;
            int qcc = min(max(qc, 0), WI - 1);
            off[r][c] = prc * WI + qcc;
            msk[r][c] = rm * cm;
        }
    }
    const float* inb = in + (size_t)(b * CI) * HI * WI;
    const float* wco = W + (size_t)co * CI * 9;
    float bb = bias[co];
    float a00 = bb, a01 = bb, a10 = bb, a11 = bb;
    const int me[3] = {0, 1, 1}, mo[3] = {1, 1, 2};
    #pragma unroll 4
    for (int ci = 0; ci < CI; ++ci) {
        const float* ip = inb + (size_t)ci * HI * WI;
        const float* wp = wco + ci * 9;
        float v[3][3];
        #pragma unroll
        for (int r = 0; r < 3; ++r)
            #pragma unroll
            for (int c = 0; c < 3; ++c)
                v[r][c] = msk[r][c] * ip[off[r][c]];
        #pragma unroll
        for (int dy = 0; dy < 3; ++dy) {
            #pragma unroll
            for (int dx = 0; dx < 3; ++dx) {
                float w = wp[dy * 3 + dx];
                a00 += w * v[me[dy]][me[dx]];
                a01 += w * v[me[dy]][mo[dx]];
                a10 += w * v[mo[dy]][me[dx]];
                a11 += w * v[mo[dy]][mo[dx]];
            }
        }
    }
    if (RELU) {
        a00 = lrelu(a00, 0.2f); a01 = lrelu(a01, 0.2f);
        a10 = lrelu(a10, 0.2f); a11 = lrelu(a11, 0.2f);
    }
    float* ob = out + ((size_t)(b * CO + co) * HO + 2 * p) * WO + 2 * q;
    float2 r0 = {a00, a01}, r1 = {a10, a11};
    *(float2*)ob = r0;
    *(float2*)(ob + WO) = r1;
}

extern "C" void kernel_launch(void* const* d_in, const int* in_sizes, int n_in,
                              void* d_out, int out_size, void* d_ws, size_t ws_size,
                              hipStream_t stream) {
    const float* x   = (const float*)d_in[0];
    const float* Wc  = (const float*)d_in[1];
    const float* bc  = (const float*)d_in[2];
    const float* W1  = (const float*)d_in[3];
    const float* b1  = (const float*)d_in[4];
    const float* W2  = (const float*)d_in[5];
    const float* b2  = (const float*)d_in[6];
    const float* W3  = (const float*)d_in[7];
    const float* b3  = (const float*)d_in[8];
    const float* W4  = (const float*)d_in[9];
    const float* b4  = (const float*)d_in[10];
    const float* W5  = (const float*)d_in[11];
    const float* b5  = (const float*)d_in[12];
    const float* Wfc = (const float*)d_in[13];
    const float* bfc = (const float*)d_in[14];
    const float* Wd1 = (const float*)d_in[15];
    const float* bd1 = (const float*)d_in[16];
    const float* Wd2 = (const float*)d_in[17];
    const float* bd2 = (const float*)d_in[18];
    const float* Wd3 = (const float*)d_in[19];
    const float* bd3 = (const float*)d_in[20];
    float* out = (float*)d_out;

    const long NST = (long)N_PTS * N_PTS;
    const size_t TAIL_SZ = 12214272ull;
    const size_t NEED_BATCHED = 16809984ull + 33554432ull + TAIL_SZ;  // 62,578,688
    const bool batched = ws_size >= NEED_BATCHED;
    const size_t negd_bytes = batched ? 33554432ull : 16777216ull;

    char* ws = (char*)d_ws;
    float* Hb   = (float*)(ws + 0);          // (B,N,2)
    float* CAT  = (float*)(ws + 32768);      // (B,N,512) fp32  8 MB
    float* YaT  = (float*)(ws + 8421376);    // (B,N,256)       4 MB
    float* ZT   = (float*)(ws + 12615680);   // (B,N,256)       4 MB
    float* NEGD = (float*)(ws + 16809984);   // (B?,N,N)     16/32 MB
    char* tail  = ws + 16809984 + negd_bytes;
    float* XX   = (float*)(tail);            // 16 KB
    int*   IDX  = (int*)  (tail + 16384);    // 640 KB
    float* PART = (float*)(tail + 671744);   // 128 KB
    float* G    = (float*)(tail + 802816);   // 8 KB
    float* D0   = (float*)(tail + 811008);   // 128 KB
    float* DEC1 = (float*)(tail + 942080);   // 256 KB
    float* DEC2 = (float*)(tail + 1204224);  // 512 KB
    short* W5h  = (short*)(tail + 1728512);  // 1 MB
    short* W5l  = (short*)(tail + 2777088);  // 1 MB
    short* CATh = (short*)(tail + 3825664);  // (B,N,512) bf16  4 MB
    short* CATl = (short*)(tail + 8019968);  // 4 MB

    // prefix + W5 split (both depend only on inputs)
    prefix_cvt_kernel<<<528, 256, 0, stream>>>(x, Wc, bc, Hb, W5, W5h, W5l);

    if (batched) {
        // ---- stage 1: C=2, O=64 ----
        gram_small_kernel<<<dim3(32, 32, 2), 256, 0, stream>>>(Hb, (long)N_PTS * 2, NST, NEGD);
        topk_kernel<1><<<dim3(N_PTS, 2), 256, 0, stream>>>(NEGD, NST, IDX);
        ya_z_kernel<2, 64, 1><<<dim3(128, 1, BATCH), 256, 0, stream>>>(Hb, 2, (long)N_PTS * 2,
                                                                       W1, b1, YaT, ZT);
        edge_reduce_kernel<64, 1, 1><<<dim3(128, BATCH), 256, 0, stream>>>(YaT, ZT, IDX, CAT,
                                                                           CATh, CATl, XX, 0);
        // ---- stage 2: C=64 (slice 0:64), O=64 ----
        gram_mfma_kernel<64, 2><<<dim3(16, 16, 2), 256, 0, stream>>>(
            CATh + 0, CATl + 0, (long)N_PTS * 512, 512, XX, N_PTS, NEGD, NST);
        topk_kernel<2><<<dim3(N_PTS, 2), 256, 0, stream>>>(NEGD, NST, IDX);
        ya_z_kernel<64, 64, 2><<<dim3(128, 1, BATCH), 256, 0, stream>>>(CAT + 0, 512,
                                                                        (long)N_PTS * 512,
                                                                        W2, b2, YaT, ZT);
        edge_reduce_kernel<64, 2, 1><<<dim3(128, BATCH), 256, 0, stream>>>(YaT, ZT, IDX, CAT,
                                                                           CATh, CATl, XX, 64);
        // ---- stage 3: C=64 (slice 64:128), O=128 ----
        gram_mfma_kernel<64, 3><<<dim3(16, 16, 2), 256, 0, stream>>>(
            CATh + 64, CATl + 64, (long)N_PTS * 512, 512, XX, N_PTS, NEGD, NST);
        topk_kernel<3><<<dim3(N_PTS, 2), 256, 0, stream>>>(NEGD, NST, IDX);
        ya_z_kernel<64, 128, 3><<<dim3(128, 2, BATCH), 256, 0, stream>>>(CAT + 64, 512,
                                                                         (long)N_PTS * 512,
                                                                         W3, b3, YaT, ZT);
        edge_reduce_kernel<128, 3, 1><<<dim3(256, BATCH), 256, 0, stream>>>(YaT, ZT, IDX, CAT,
                                                                            CATh, CATl, XX, 128);
        // ---- stage 4: C=128 (slice 128:256), O=256 ----
        gram_mfma_kernel<128, 4><<<dim3(16, 16, 2), 256, 0, stream>>>(
            CATh + 128, CATl + 128, (long)N_PTS * 512, 512, XX, N_PTS, NEGD, NST);
        topk_kernel<4><<<dim3(N_PTS, 2), 256, 0, stream>>>(NEGD, NST, IDX);
        ya_z_kernel<128, 256, 4><<<dim3(128, 4, BATCH), 256, 0, stream>>>(CAT + 128, 512,
                                                                          (long)N_PTS * 512,
                                                                          W4, b4, YaT, ZT);
        edge_reduce_kernel<256, 4, 0><<<dim3(512, BATCH), 256, 0, stream>>>(YaT, ZT, IDX, CAT,
                                                                            CATh, CATl, XX, 256);
    } else {
        // fallback: sequential per-batch (NEGD holds one batch)
        for (int b = 0; b < BATCH; ++b) {
            gram_small_kernel<<<dim3(32, 32, 1), 256, 0, stream>>>(Hb + (size_t)b * N_PTS * 2, 0,
                                                                   0, NEGD);
            topk_kernel<1><<<dim3(N_PTS, 1), 256, 0, stream>>>(NEGD, 0,
                                                               IDX + (size_t)b * N_PTS * KNN);
        }
        ya_z_kernel<2, 64, 1><<<dim3(128, 1, BATCH), 256, 0, stream>>>(Hb, 2, (long)N_PTS * 2,
                                                                       W1, b1, YaT, ZT);
        edge_reduce_kernel<64, 1, 1><<<dim3(128, BATCH), 256, 0, stream>>>(YaT, ZT, IDX, CAT,
                                                                           CATh, CATl, XX, 0);
        for (int b = 0; b < BATCH; ++b) {
            gram_mfma_kernel<64, 2><<<dim3(16, 16, 1), 256, 0, stream>>>(
                CATh + 0 + (size_t)b * N_PTS * 512, CATl + 0 + (size_t)b * N_PTS * 512, 0, 512,
                XX + b * N_PTS, 0, NEGD, 0);
            topk_kernel<2><<<dim3(N_PTS, 1), 256, 0, stream>>>(NEGD, 0,
                                                               IDX + (size_t)b * N_PTS * KNN);
        }
        ya_z_kernel<64, 64, 2><<<dim3(128, 1, BATCH), 256, 0, stream>>>(CAT + 0, 512,
                                                                        (long)N_PTS * 512,
                                                                        W2, b2, YaT, ZT);
        edge_reduce_kernel<64, 2, 1><<<dim3(128, BATCH), 256, 0, stream>>>(YaT, ZT, IDX, CAT,
                                                                           CATh, CATl, XX, 64);
        for (int b = 0; b < BATCH; ++b) {
            gram_mfma_kernel<64, 3><<<dim3(16, 16, 1), 256, 0, stream>>>(
                CATh + 64 + (size_t)b * N_PTS * 512, CATl + 64 + (size_t)b * N_PTS * 512, 0, 512,
                XX + b * N_PTS, 0, NEGD, 0);
            topk_kernel<3><<<dim3(N_PTS, 1), 256, 0, stream>>>(NEGD, 0,
                                                               IDX + (size_t)b * N_PTS * KNN);
        }
        ya_z_kernel<64, 128, 3><<<dim3(128, 2, BATCH), 256, 0, stream>>>(CAT + 64, 512,
                                                                         (long)N_PTS * 512,
                                                                         W3, b3, YaT, ZT);
        edge_reduce_kernel<128, 3, 1><<<dim3(256, BATCH), 256, 0, stream>>>(YaT, ZT, IDX, CAT,
                                                                            CATh, CATl, XX, 128);
        for (int b = 0; b < BATCH; ++b) {
            gram_mfma_kernel<128, 4><<<dim3(16, 16, 1), 256, 0, stream>>>(
                CATh + 128 + (size_t)b * N_PTS * 512, CATl + 128 + (size_t)b * N_PTS * 512, 0, 512,
                XX + b * N_PTS, 0, NEGD, 0);
            topk_kernel<4><<<dim3(N_PTS, 1), 256, 0, stream>>>(NEGD, 0,
                                                               IDX + (size_t)b * N_PTS * KNN);
        }
        ya_z_kernel<128, 256, 4><<<dim3(128, 4, BATCH), 256, 0, stream>>>(CAT + 128, 512,
                                                                          (long)N_PTS * 512,
                                                                          W4, b4, YaT, ZT);
        edge_reduce_kernel<256, 4, 0><<<dim3(512, BATCH), 256, 0, stream>>>(YaT, ZT, IDX, CAT,
                                                                            CATh, CATl, XX, 256);
    }

    // ---- global feature: W5 MFMA + max (W5h/W5l prepared at start) ----
    w5max_mfma_kernel<<<dim3(16, 8, BATCH), 256, 0, stream>>>(CATh, CATl, W5h, W5l, b5, PART);
    greduce_kernel<<<8, 256, 0, stream>>>(PART, G);
    fc_kernel<<<4096, 256, 0, stream>>>(G, Wfc, bfc, D0);

    // ---- decoder: quad upconvs ----
    upconv_quad_kernel<64, 32, 16, 16, 1><<<dim3(1, 32, BATCH), 256, 0, stream>>>(D0, Wd1, bd1,
                                                                                  DEC1);
    upconv_quad_kernel<32, 16, 32, 32, 1><<<dim3(4, 16, BATCH), 256, 0, stream>>>(DEC1, Wd2, bd2,
                                                                                  DEC2);
    upconv_quad_kernel<16, 1, 64, 64, 0><<<dim3(16, 1, BATCH), 256, 0, stream>>>(DEC2, Wd3, bd3,
                                                                                 out);
}